// Round 2
// baseline (264.352 us; speedup 1.0000x reference)
//
#include <hip/hip_runtime.h>
#include <hip/hip_bf16.h>

#define B_ 4
#define T_ 2048
#define C_ 1024
#define H_ 16
#define D_ 64
#define N3_ 3072
#define M_ (B_*T_)

typedef __bf16 bf16x8 __attribute__((ext_vector_type(8)));
typedef float f32x4 __attribute__((ext_vector_type(4)));

__device__ __forceinline__ unsigned short f2bf(float f){
  __bf16 h = (__bf16)f;              // RNE fptrunc -> v_cvt on gfx950
  return __builtin_bit_cast(unsigned short, h);
}
__device__ __forceinline__ unsigned int pk2(float a, float b){
  return (unsigned int)f2bf(a) | ((unsigned int)f2bf(b)<<16);
}
// async global->LDS, 16B per lane; LDS dest = base + lane*16 (wave-uniform base)
__device__ __forceinline__ void gload_lds16(const unsigned short* g, unsigned short* l){
  __builtin_amdgcn_global_load_lds(
      (const __attribute__((address_space(1))) void*)g,
      (__attribute__((address_space(3))) void*)l, 16, 0, 0);
}

// ---------------- x fp32 -> bf16 one-time convert ---------------------------
__global__ __launch_bounds__(256) void x_cvt(
    const float* __restrict__ X, unsigned short* __restrict__ Xb)
{
  const size_t i = ((size_t)blockIdx.x*256 + threadIdx.x)*8;
  float4 f0 = *(const float4*)(X+i);
  float4 f1 = *(const float4*)(X+i+4);
  uint4 w = make_uint4(pk2(f0.x,f0.y), pk2(f0.z,f0.w), pk2(f1.x,f1.y), pk2(f1.z,f1.w));
  *(uint4*)(Xb+i) = w;
}

// ---------------- transpose + fp32->bf16 convert: src[K][N] -> dst[N][K] ----
__global__ __launch_bounds__(256) void transpose_cvt(
    const float* __restrict__ src, unsigned short* __restrict__ dst, int K, int N)
{
  __shared__ float tile[32][33];
  const int tx = threadIdx.x & 31, ty = threadIdx.x >> 5; // 32 x 8
  const int nt = blockIdx.x * 32, kt = blockIdx.y * 32;
  #pragma unroll
  for (int i=0;i<32;i+=8) tile[ty+i][tx] = src[(size_t)(kt+ty+i)*N + nt+tx];
  __syncthreads();
  #pragma unroll
  for (int i=0;i<32;i+=8) dst[(size_t)(nt+ty+i)*K + kt+tx] = f2bf(tile[tx][ty+i]);
}

// ---------------- QKV GEMM (m97-style global_load_lds staging) --------------
// T1 (m192): XCD-chunked swizzle on flat grid 1536 (1536%8==0 -> bijective).
// XCD i gets contiguous tiles = 8 m-rows x all 24 n-cols -> A working set
// per XCD 2MB (L2-resident) instead of 16MB scattered.
__global__ __launch_bounds__(256) void qkv_gemm(
    const unsigned short* __restrict__ Xb, const unsigned short* __restrict__ Wt,
    const float* __restrict__ bias,
    unsigned short* __restrict__ Qb, unsigned short* __restrict__ Kb,
    unsigned short* __restrict__ Vt)
{
  __shared__ __align__(16) unsigned short As[128][32];
  __shared__ __align__(16) unsigned short Bs[128][32];
  const int tid = threadIdx.x;
  const int nbx = N3_/128;                       // 24
  const int cpx = (nbx*(M_/128))/8;              // 192 tiles per XCD
  const int id0 = (int)blockIdx.x;
  const int swz = (id0 & 7)*cpx + (id0 >> 3);
  const int m0 = (swz / nbx)*128, n0 = (swz % nbx)*128;
  const int wv = tid>>6, lane = tid&63, lm = lane&15, lq = lane>>4;
  const int wr = wv>>1, wc = wv&1;
  f32x4 acc[4][4] = {};
  const int schunk = (lane&3) ^ ((lane>>3)&3);
  const unsigned short* gA = Xb + (size_t)(m0 + wv*32 + (lane>>2))*C_ + schunk*8;
  const unsigned short* gB = Wt + (size_t)(n0 + wv*32 + (lane>>2))*C_ + schunk*8;
  unsigned short* lA0 = &As[wv*32][0];
  unsigned short* lA1 = &As[wv*32+16][0];
  unsigned short* lB0 = &Bs[wv*32][0];
  unsigned short* lB1 = &Bs[wv*32+16][0];
  const int rkey = (lm>>1)&3;
  for (int k0=0;k0<C_;k0+=32){
    __syncthreads();
    gload_lds16(gA + k0,            lA0);
    gload_lds16(gA + 16*C_ + k0,    lA1);
    gload_lds16(gB + k0,            lB0);
    gload_lds16(gB + 16*C_ + k0,    lB1);
    __syncthreads();
    bf16x8 a[4], b[4];
    #pragma unroll
    for (int mt=0;mt<4;mt++) a[mt] = *(const bf16x8*)&As[wr*64+mt*16+lm][(lq^rkey)*8];
    #pragma unroll
    for (int nt=0;nt<4;nt++) b[nt] = *(const bf16x8*)&Bs[wc*64+nt*16+lm][(lq^rkey)*8];
    #pragma unroll
    for (int mt=0;mt<4;mt++)
      #pragma unroll
      for (int nt=0;nt<4;nt++)
        acc[mt][nt] = __builtin_amdgcn_mfma_f32_16x16x32_bf16(a[mt], b[nt], acc[mt][nt], 0,0,0);
  }
  const int sel = n0>>10;  // block-uniform: 0=Q,1=K,2=V
  const float qsc = (sel==0) ? 0.18033688f : 1.0f;  // 0.125*log2(e) folded into Q
  #pragma unroll
  for (int mt=0;mt<4;mt++){
    const int grow = m0 + wr*64 + mt*16 + lq*4;
    const int bb = grow>>11, tt0 = grow&2047;
    #pragma unroll
    for (int nt=0;nt<4;nt++){
      const int gcol = n0 + wc*64 + nt*16 + lm;
      const int hh = (gcol>>6)&15, dd = gcol&63;
      const float bv = bias[gcol];
      if (sel==2){
        ushort4 pv;
        pv.x = f2bf(acc[mt][nt][0] + bv);
        pv.y = f2bf(acc[mt][nt][1] + bv);
        pv.z = f2bf(acc[mt][nt][2] + bv);
        pv.w = f2bf(acc[mt][nt][3] + bv);
        *(ushort4*)&Vt[ ((size_t)(bb*H_+hh)*D_ + dd)*T_ + tt0 ] = pv;
      } else {
        unsigned short* dst = (sel==0) ? Qb : Kb;
        #pragma unroll
        for (int r=0;r<4;r++)
          dst[ ((size_t)(bb*H_+hh)*T_ + tt0 + r)*D_ + dd ] = f2bf((acc[mt][nt][r] + bv)*qsc);
      }
    }
  }
}

// ---------------- flash attention -------------------------------------------
// Double-buffered async K/V staging (DMA issued one iter ahead), dedicated
// swizzled P buffer -> ONE barrier per iteration; O computed transposed.
// Grid flat 2048: bh = id&63 (XCD L2 locality), qi = 31-(id>>6) (heavy first).
// T5: s_setprio(1) around both MFMA clusters (4 blocks/CU at independent
// j-phases -> scheduler role diversity; m191 attn +4-7%).
__global__ __launch_bounds__(256, 4) void flash_attn(
    const unsigned short* __restrict__ Qb, const unsigned short* __restrict__ Kb,
    const unsigned short* __restrict__ Vt, unsigned short* __restrict__ Yb)
{
  __shared__ __align__(16) unsigned short Ks[2][64][64]; // swizzled chunks
  __shared__ __align__(16) unsigned short Vs[2][64][64]; // V^T, swizzled
  __shared__ __align__(16) unsigned short Ps[64][64];    // P, swizzled, wave-local rows
  const int tid = threadIdx.x;
  const int wv = tid>>6, lane = tid&63, lm = lane&15, lq = lane>>4;
  const int id = (int)blockIdx.x;
  const int bh = id & 63;
  const int qi = 31 - (id >> 6);
  const int qbase = qi*64;
  const unsigned short* Qh = Qb + (size_t)bh*T_*D_;
  const unsigned short* Kh = Kb + (size_t)bh*T_*D_;
  const unsigned short* Vh = Vt + (size_t)bh*D_*T_;
  bf16x8 aq[2];
  {
    const int q = qbase + wv*16 + lm;
    aq[0] = *(const bf16x8*)&Qh[(size_t)q*D_ + lq*8];
    aq[1] = *(const bf16x8*)&Qh[(size_t)q*D_ + 32 + lq*8];
  }
  f32x4 o[4] = {};
  float l_r[4] = {0.f,0.f,0.f,0.f};
  // staging: wave wv covers rows [wv*16, wv*16+16) in two 8-row DMA issues;
  // lane -> row wv*16 + 8*is + (lane>>3), stored chunk lane&7,
  // source chunk (lane&7)^(row&7)
  const int srl = lane>>3;
  const int sc  = (lane&7) ^ srl;
  const unsigned short* kg = Kh + (size_t)(wv*16 + srl)*D_ + sc*8;
  const unsigned short* vg = Vh + (size_t)(wv*16 + srl)*T_ + sc*8;
  const int keyR = lm&7;   // read swizzle key for LDS rows ...*16+lm
  // issue DMA for tile 0 into buffer 0
  {
    unsigned short* lk = &Ks[0][wv*16][0];
    unsigned short* lv = &Vs[0][wv*16][0];
    gload_lds16(kg,            lk);
    gload_lds16(kg + 8*D_,     lk + 8*64);
    gload_lds16(vg,            lv);
    gload_lds16(vg + 8*T_,     lv + 8*64);
  }
  for (int j=0;j<=qi;j++){
    const int cb = j&1;
    __syncthreads();   // drains this wave's DMA (tile j) + prev-iter LDS reads;
                       // makes tile j visible to all waves
    if (j < qi){       // prefetch tile j+1 into the other buffer (hidden)
      unsigned short* lk = &Ks[cb^1][wv*16][0];
      unsigned short* lv = &Vs[cb^1][wv*16][0];
      gload_lds16(kg + (size_t)((j+1)*64  )*D_, lk);
      gload_lds16(kg + (size_t)((j+1)*64+8)*D_, lk + 8*64);
      gload_lds16(vg + (j+1)*64,                lv);
      gload_lds16(vg + 8*T_ + (j+1)*64,         lv + 8*64);
    }
    // S = Q K^T  (per wave: 16 q rows x 64 keys)
    f32x4 s[4] = {};
    __builtin_amdgcn_s_setprio(1);
    #pragma unroll
    for (int nt=0;nt<4;nt++){
      bf16x8 bk0 = *(const bf16x8*)&Ks[cb][nt*16+lm][((lq  )^keyR)*8];
      bf16x8 bk1 = *(const bf16x8*)&Ks[cb][nt*16+lm][((lq+4)^keyR)*8];
      s[nt] = __builtin_amdgcn_mfma_f32_16x16x32_bf16(aq[0], bk0, s[nt], 0,0,0);
      s[nt] = __builtin_amdgcn_mfma_f32_16x16x32_bf16(aq[1], bk1, s[nt], 0,0,0);
    }
    __builtin_amdgcn_s_setprio(0);
    // p = exp2(s) (Q pre-scaled); causal mask only on diagonal tile
    if (j==qi){
      const int qrow0 = wv*16 + lq*4;
      #pragma unroll
      for (int nt=0;nt<4;nt++){
        const int col = nt*16+lm;
        #pragma unroll
        for (int r=0;r<4;r++)
          s[nt][r] = (col <= qrow0+r) ? exp2f(s[nt][r]) : 0.f;
      }
    } else {
      #pragma unroll
      for (int nt=0;nt<4;nt++)
        #pragma unroll
        for (int r=0;r<4;r++)
          s[nt][r] = exp2f(s[nt][r]);
    }
    #pragma unroll
    for (int r=0;r<4;r++)
      l_r[r] += (s[0][r]+s[1][r]) + (s[2][r]+s[3][r]);
    // P -> dedicated LDS (C layout, swizzled chunks); rows wave-local -> no barrier
    #pragma unroll
    for (int nt=0;nt<4;nt++)
      #pragma unroll
      for (int r=0;r<4;r++){
        const int row = wv*16 + lq*4 + r;
        const int ch  = (2*nt + (lm>>3)) ^ (row&7);
        Ps[row][ch*8 + (lm&7)] = f2bf(s[nt][r]);
      }
    // O^T += V^T P^T : mfma(A=V-frag, B=P-frag) -> D[m=d][n=q]
    __builtin_amdgcn_s_setprio(1);
    #pragma unroll
    for (int kc=0;kc<2;kc++){
      bf16x8 ap = *(const bf16x8*)&Ps[wv*16+lm][((kc*4+lq)^keyR)*8];
      #pragma unroll
      for (int dt=0;dt<4;dt++){
        bf16x8 bv = *(const bf16x8*)&Vs[cb][dt*16+lm][((kc*4+lq)^keyR)*8];
        o[dt] = __builtin_amdgcn_mfma_f32_16x16x32_bf16(bv, ap, o[dt], 0,0,0);
      }
    }
    __builtin_amdgcn_s_setprio(0);
  }
  // l: reduce across 16 lm-lanes, then broadcast to transposed layout (q=lm)
  #pragma unroll
  for (int r=0;r<4;r++){
    float rs = l_r[r];
    rs += __shfl_xor(rs,1); rs += __shfl_xor(rs,2);
    rs += __shfl_xor(rs,4); rs += __shfl_xor(rs,8);
    l_r[r] = rs;
  }
  const int srcl = (lm>>2)<<4;  // lane holding row q=lm
  float lv0v = __shfl(l_r[0], srcl);
  float lv1v = __shfl(l_r[1], srcl);
  float lv2v = __shfl(l_r[2], srcl);
  float lv3v = __shfl(l_r[3], srcl);
  const int rr = lm&3;
  float linv = (rr==0) ? lv0v : (rr==1) ? lv1v : (rr==2) ? lv2v : lv3v;
  linv = 1.0f/linv;
  const int bb = bh>>4, hh = bh&15;
  const int q = qbase + wv*16 + lm;
  #pragma unroll
  for (int dt=0;dt<4;dt++){
    ushort4 y;
    y.x = f2bf(o[dt][0]*linv);
    y.y = f2bf(o[dt][1]*linv);
    y.z = f2bf(o[dt][2]*linv);
    y.w = f2bf(o[dt][3]*linv);
    *(ushort4*)&Yb[ ((size_t)bb*T_ + q)*C_ + hh*64 + dt*16 + lq*4 ] = y;
  }
}

// ---------------- proj GEMM (m97-style): Yb x Wpt^T -> fp32 out + bias ------
// T1 swizzle: flat grid 512 (512%8==0 -> bijective chunked swizzle).
__global__ __launch_bounds__(256) void proj_gemm(
    const unsigned short* __restrict__ Yb, const unsigned short* __restrict__ Wt,
    const float* __restrict__ bias, float* __restrict__ Out)
{
  __shared__ __align__(16) unsigned short As[128][32];
  __shared__ __align__(16) unsigned short Bs[128][32];
  const int tid = threadIdx.x;
  const int nbx = C_/128;                        // 8
  const int cpx = (nbx*(M_/128))/8;              // 64 tiles per XCD
  const int id0 = (int)blockIdx.x;
  const int swz = (id0 & 7)*cpx + (id0 >> 3);
  const int m0 = (swz / nbx)*128, n0 = (swz % nbx)*128;
  const int wv = tid>>6, lane = tid&63, lm = lane&15, lq = lane>>4;
  const int wr = wv>>1, wc = wv&1;
  f32x4 acc[4][4] = {};
  const int schunk = (lane&3) ^ ((lane>>3)&3);
  const unsigned short* gA = Yb + (size_t)(m0 + wv*32 + (lane>>2))*C_ + schunk*8;
  const unsigned short* gB = Wt + (size_t)(n0 + wv*32 + (lane>>2))*C_ + schunk*8;
  unsigned short* lA0 = &As[wv*32][0];
  unsigned short* lA1 = &As[wv*32+16][0];
  unsigned short* lB0 = &Bs[wv*32][0];
  unsigned short* lB1 = &Bs[wv*32+16][0];
  const int rkey = (lm>>1)&3;
  for (int k0=0;k0<C_;k0+=32){
    __syncthreads();
    gload_lds16(gA + k0,            lA0);
    gload_lds16(gA + 16*C_ + k0,    lA1);
    gload_lds16(gB + k0,            lB0);
    gload_lds16(gB + 16*C_ + k0,    lB1);
    __syncthreads();
    bf16x8 a[4], b[4];
    #pragma unroll
    for (int mt=0;mt<4;mt++) a[mt] = *(const bf16x8*)&As[wr*64+mt*16+lm][(lq^rkey)*8];
    #pragma unroll
    for (int nt=0;nt<4;nt++) b[nt] = *(const bf16x8*)&Bs[wc*64+nt*16+lm][(lq^rkey)*8];
    #pragma unroll
    for (int mt=0;mt<4;mt++)
      #pragma unroll
      for (int nt=0;nt<4;nt++)
        acc[mt][nt] = __builtin_amdgcn_mfma_f32_16x16x32_bf16(a[mt], b[nt], acc[mt][nt], 0,0,0);
  }
  #pragma unroll
  for (int mt=0;mt<4;mt++){
    const int grow = m0 + wr*64 + mt*16 + lq*4;
    #pragma unroll
    for (int nt=0;nt<4;nt++){
      const int gcol = n0 + wc*64 + nt*16 + lm;
      const float bv = bias[gcol];
      #pragma unroll
      for (int r=0;r<4;r++)
        Out[(size_t)(grow+r)*C_ + gcol] = acc[mt][nt][r] + bv;
    }
  }
}

extern "C" void kernel_launch(void* const* d_in, const int* in_sizes, int n_in,
                              void* d_out, int out_size, void* d_ws, size_t ws_size,
                              hipStream_t stream)
{
  const float* x      = (const float*)d_in[0];
  const float* W_attn = (const float*)d_in[1];
  const float* b_attn = (const float*)d_in[2];
  const float* W_proj = (const float*)d_in[3];
  const float* b_proj = (const float*)d_in[4];
  float* out = (float*)d_out;

  unsigned short* Wat = (unsigned short*)d_ws;            // [3072][1024] bf16
  unsigned short* Wpt = Wat + (size_t)N3_*C_;             // [1024][1024] bf16
  unsigned short* Xb  = Wpt + (size_t)C_*C_;              // [M,1024]  bf16
  unsigned short* Qb  = Xb  + (size_t)M_*C_;              // [B,H,T,D] bf16 (pre-scaled)
  unsigned short* Kb  = Qb  + (size_t)M_*C_;              // [B,H,T,D] bf16
  unsigned short* Vt  = Kb  + (size_t)M_*C_;              // [B,H,D,T] bf16
  unsigned short* Yb  = Vt  + (size_t)M_*C_;              // [M,1024]  bf16
  (void)ws_size; (void)in_sizes; (void)n_in; (void)out_size;

  x_cvt        <<<dim3(M_*C_/2048),        256, 0, stream>>>(x, Xb);
  transpose_cvt<<<dim3(N3_/32, C_/32),     256, 0, stream>>>(W_attn, Wat, C_, N3_);
  transpose_cvt<<<dim3(C_/32,  C_/32),     256, 0, stream>>>(W_proj, Wpt, C_, C_);
  qkv_gemm     <<<dim3((N3_/128)*(M_/128)), 256, 0, stream>>>(Xb, Wat, b_attn, Qb, Kb, Vt);
  flash_attn   <<<dim3(2048),              256, 0, stream>>>(Qb, Kb, Vt, Yb);
  proj_gemm    <<<dim3((C_/128)*(M_/128)),  256, 0, stream>>>(Yb, Wpt, b_proj, out);
}

// Round 7
// 251.225 us; speedup vs baseline: 1.0523x; 1.0523x over previous
//
#include <hip/hip_runtime.h>
#include <hip/hip_bf16.h>

#define B_ 4
#define T_ 2048
#define C_ 1024
#define H_ 16
#define D_ 64
#define N3_ 3072
#define M_ (B_*T_)

typedef __bf16 bf16x8 __attribute__((ext_vector_type(8)));
typedef float f32x4 __attribute__((ext_vector_type(4)));
typedef float f32x16 __attribute__((ext_vector_type(16)));

__device__ __forceinline__ unsigned short f2bf(float f){
  __bf16 h = (__bf16)f;              // RNE fptrunc -> v_cvt on gfx950
  return __builtin_bit_cast(unsigned short, h);
}
__device__ __forceinline__ unsigned int pk2(float a, float b){
  return (unsigned int)f2bf(a) | ((unsigned int)f2bf(b)<<16);
}
// async global->LDS, 16B per lane; LDS dest = base + lane*16 (wave-uniform base)
__device__ __forceinline__ void gload_lds16(const unsigned short* g, unsigned short* l){
  __builtin_amdgcn_global_load_lds(
      (const __attribute__((address_space(1))) void*)g,
      (__attribute__((address_space(3))) void*)l, 16, 0, 0);
}

// ---------------- x fp32 -> bf16 one-time convert ---------------------------
__global__ __launch_bounds__(256) void x_cvt(
    const float* __restrict__ X, unsigned short* __restrict__ Xb)
{
  const size_t i = ((size_t)blockIdx.x*256 + threadIdx.x)*8;
  float4 f0 = *(const float4*)(X+i);
  float4 f1 = *(const float4*)(X+i+4);
  uint4 w = make_uint4(pk2(f0.x,f0.y), pk2(f0.z,f0.w), pk2(f1.x,f1.y), pk2(f1.z,f1.w));
  *(uint4*)(Xb+i) = w;
}

// ---------------- transpose + fp32->bf16 convert: src[K][N] -> dst[N][K] ----
__global__ __launch_bounds__(256) void transpose_cvt(
    const float* __restrict__ src, unsigned short* __restrict__ dst, int K, int N)
{
  __shared__ float tile[32][33];
  const int tx = threadIdx.x & 31, ty = threadIdx.x >> 5; // 32 x 8
  const int nt = blockIdx.x * 32, kt = blockIdx.y * 32;
  #pragma unroll
  for (int i=0;i<32;i+=8) tile[ty+i][tx] = src[(size_t)(kt+ty+i)*N + nt+tx];
  __syncthreads();
  #pragma unroll
  for (int i=0;i<32;i+=8) dst[(size_t)(nt+ty+i)*K + kt+tx] = f2bf(tile[tx][ty+i]);
}

// ---------------- QKV GEMM (m97-style global_load_lds staging) --------------
// T1 (m192): XCD-chunked swizzle on flat grid 1536 (1536%8==0 -> bijective).
__global__ __launch_bounds__(256) void qkv_gemm(
    const unsigned short* __restrict__ Xb, const unsigned short* __restrict__ Wt,
    const float* __restrict__ bias,
    unsigned short* __restrict__ Qb, unsigned short* __restrict__ Kb,
    unsigned short* __restrict__ Vt)
{
  __shared__ __align__(16) unsigned short As[128][32];
  __shared__ __align__(16) unsigned short Bs[128][32];
  const int tid = threadIdx.x;
  const int nbx = N3_/128;                       // 24
  const int cpx = (nbx*(M_/128))/8;              // 192 tiles per XCD
  const int id0 = (int)blockIdx.x;
  const int swz = (id0 & 7)*cpx + (id0 >> 3);
  const int m0 = (swz / nbx)*128, n0 = (swz % nbx)*128;
  const int wv = tid>>6, lane = tid&63, lm = lane&15, lq = lane>>4;
  const int wr = wv>>1, wc = wv&1;
  f32x4 acc[4][4] = {};
  const int schunk = (lane&3) ^ ((lane>>3)&3);
  const unsigned short* gA = Xb + (size_t)(m0 + wv*32 + (lane>>2))*C_ + schunk*8;
  const unsigned short* gB = Wt + (size_t)(n0 + wv*32 + (lane>>2))*C_ + schunk*8;
  unsigned short* lA0 = &As[wv*32][0];
  unsigned short* lA1 = &As[wv*32+16][0];
  unsigned short* lB0 = &Bs[wv*32][0];
  unsigned short* lB1 = &Bs[wv*32+16][0];
  const int rkey = (lm>>1)&3;
  for (int k0=0;k0<C_;k0+=32){
    __syncthreads();
    gload_lds16(gA + k0,            lA0);
    gload_lds16(gA + 16*C_ + k0,    lA1);
    gload_lds16(gB + k0,            lB0);
    gload_lds16(gB + 16*C_ + k0,    lB1);
    __syncthreads();
    bf16x8 a[4], b[4];
    #pragma unroll
    for (int mt=0;mt<4;mt++) a[mt] = *(const bf16x8*)&As[wr*64+mt*16+lm][(lq^rkey)*8];
    #pragma unroll
    for (int nt=0;nt<4;nt++) b[nt] = *(const bf16x8*)&Bs[wc*64+nt*16+lm][(lq^rkey)*8];
    #pragma unroll
    for (int mt=0;mt<4;mt++)
      #pragma unroll
      for (int nt=0;nt<4;nt++)
        acc[mt][nt] = __builtin_amdgcn_mfma_f32_16x16x32_bf16(a[mt], b[nt], acc[mt][nt], 0,0,0);
  }
  const int sel = n0>>10;  // block-uniform: 0=Q,1=K,2=V
  const float qsc = (sel==0) ? 0.18033688f : 1.0f;  // 0.125*log2(e) folded into Q
  #pragma unroll
  for (int mt=0;mt<4;mt++){
    const int grow = m0 + wr*64 + mt*16 + lq*4;
    const int bb = grow>>11, tt0 = grow&2047;
    #pragma unroll
    for (int nt=0;nt<4;nt++){
      const int gcol = n0 + wc*64 + nt*16 + lm;
      const int hh = (gcol>>6)&15, dd = gcol&63;
      const float bv = bias[gcol];
      if (sel==2){
        ushort4 pv;
        pv.x = f2bf(acc[mt][nt][0] + bv);
        pv.y = f2bf(acc[mt][nt][1] + bv);
        pv.z = f2bf(acc[mt][nt][2] + bv);
        pv.w = f2bf(acc[mt][nt][3] + bv);
        *(ushort4*)&Vt[ ((size_t)(bb*H_+hh)*D_ + dd)*T_ + tt0 ] = pv;
      } else {
        unsigned short* dst = (sel==0) ? Qb : Kb;
        #pragma unroll
        for (int r=0;r<4;r++)
          dst[ ((size_t)(bb*H_+hh)*T_ + tt0 + r)*D_ + dd ] = f2bf((acc[mt][nt][r] + bv)*qsc);
      }
    }
  }
}

// ---------------- flash attention (32x32 swapped-QK^T, in-register P) -------
// Per block: 128 q-rows, 4 waves x 32 q each. Swapped QK^T: s = mfma(K, Q)
// -> lane holds P[key][q=lane&31] (m74/m101 D-layout). P -> PV B-frag built
// in-register via v_cvt_pk_bf16_f32 + v_permlane32_swap_b32 (T12): swap
// exchanges key-halves between lane and lane^32 (same q). No Ps LDS buffer,
// no scalar cvt/ds_write chain, denominator = in-lane sum + 1 shfl_xor(32).
// Staging/double-buffer skeleton unchanged from verified version.
#define PV_CHUNK(SV, KG, C16) do{                                              \
  unsigned int X0_, X1_, Y0_, Y1_;                                             \
  asm("v_cvt_pk_bf16_f32 %0, %1, %2" : "=v"(X0_)                               \
      : "v"((float)(SV)[(C16)*8+0]), "v"((float)(SV)[(C16)*8+1]));             \
  asm("v_cvt_pk_bf16_f32 %0, %1, %2" : "=v"(X1_)                               \
      : "v"((float)(SV)[(C16)*8+2]), "v"((float)(SV)[(C16)*8+3]));             \
  asm("v_cvt_pk_bf16_f32 %0, %1, %2" : "=v"(Y0_)                               \
      : "v"((float)(SV)[(C16)*8+4]), "v"((float)(SV)[(C16)*8+5]));             \
  asm("v_cvt_pk_bf16_f32 %0, %1, %2" : "=v"(Y1_)                               \
      : "v"((float)(SV)[(C16)*8+6]), "v"((float)(SV)[(C16)*8+7]));             \
  asm volatile("v_permlane32_swap_b32 %0, %1" : "+v"(X0_), "+v"(Y0_));         \
  asm volatile("v_permlane32_swap_b32 %0, %1" : "+v"(X1_), "+v"(Y1_));         \
  uint4 pw_ = make_uint4(X0_, X1_, Y0_, Y1_);                                  \
  bf16x8 pf_ = __builtin_bit_cast(bf16x8, pw_);                                \
  const int ch_ = (((KG)*4 + (C16)*2 + hi) ^ l7)*8;                            \
  bf16x8 v0_ = *(const bf16x8*)&Vs[cb][l31][ch_];                              \
  bf16x8 v1_ = *(const bf16x8*)&Vs[cb][32+l31][ch_];                           \
  o0 = __builtin_amdgcn_mfma_f32_32x32x16_bf16(v0_, pf_, o0, 0,0,0);           \
  o1 = __builtin_amdgcn_mfma_f32_32x32x16_bf16(v1_, pf_, o1, 0,0,0);           \
}while(0)

__global__ __launch_bounds__(256, 3) void flash_attn(
    const unsigned short* __restrict__ Qb, const unsigned short* __restrict__ Kb,
    const unsigned short* __restrict__ Vt, unsigned short* __restrict__ Yb)
{
  __shared__ __align__(16) unsigned short Ks[2][64][64]; // swizzled chunks
  __shared__ __align__(16) unsigned short Vs[2][64][64]; // V^T, swizzled
  const int tid = threadIdx.x;
  const int wv = tid>>6, lane = tid&63;
  const int l31 = lane & 31, hi = lane >> 5, l7 = lane & 7;
  const int id = (int)blockIdx.x;
  const int bh = id & 63;                 // XCD L2 locality: same bh set per XCD
  const int qblk = 15 - (id >> 6);        // heavy q-blocks first
  const int qb = qblk*128;
  const int q0 = qb + wv*32;
  const unsigned short* Qh = Qb + (size_t)bh*T_*D_;
  const unsigned short* Kh = Kb + (size_t)bh*T_*D_;
  const unsigned short* Vh = Vt + (size_t)bh*D_*T_;
  // Q fragments (B-operand): lane holds Q[q0+l31][kc*16 + hi*8 + 0..7]
  bf16x8 aq[4];
  #pragma unroll
  for (int kc=0;kc<4;kc++)
    aq[kc] = *(const bf16x8*)&Qh[(size_t)(q0+l31)*D_ + kc*16 + hi*8];
  f32x16 o0 = {}, o1 = {};   // O^T: rows d (o0: 0-31, o1: 32-63), col q=l31
  float l_r = 0.f;
  // staging (unchanged): wave wv covers rows [wv*16, wv*16+16)
  const int srl = lane>>3;
  const int sc  = (lane&7) ^ srl;
  const unsigned short* kg = Kh + (size_t)(wv*16 + srl)*D_ + sc*8;
  const unsigned short* vg = Vh + (size_t)(wv*16 + srl)*T_ + sc*8;
  {
    unsigned short* lk = &Ks[0][wv*16][0];
    unsigned short* lv = &Vs[0][wv*16][0];
    gload_lds16(kg,        lk);
    gload_lds16(kg + 8*D_, lk + 8*64);
    gload_lds16(vg,        lv);
    gload_lds16(vg + 8*T_, lv + 8*64);
  }
  const int JT = 2*qblk + 2;
  const int jmax = 2*qblk + (wv>>1);  // waves 0,1 finish one tile early
  for (int j=0;j<JT;j++){
    const int cb = j&1;
    __syncthreads();   // drains this wave's DMA (tile j) + prev-iter LDS reads
    if (j < JT-1){     // prefetch tile j+1 (hidden under compute)
      unsigned short* lk = &Ks[cb^1][wv*16][0];
      unsigned short* lv = &Vs[cb^1][wv*16][0];
      gload_lds16(kg + (size_t)((j+1)*64  )*D_, lk);
      gload_lds16(kg + (size_t)((j+1)*64+8)*D_, lk + 8*64);
      gload_lds16(vg + (j+1)*64,                lv);
      gload_lds16(vg + 8*T_ + (j+1)*64,         lv + 8*64);
    }
    if (j <= jmax){    // wave-uniform skip of fully-masked final tile
      // S^T = K Q^T : lane holds P[key = kg*32 + (r&3)+8*(r>>2)+4*hi][q = q0+l31]
      f32x16 s0 = {}, s1 = {};
      __builtin_amdgcn_s_setprio(1);
      #pragma unroll
      for (int kc=0;kc<4;kc++){
        const int ch = ((kc*2+hi) ^ l7)*8;
        bf16x8 k0 = *(const bf16x8*)&Ks[cb][l31][ch];
        bf16x8 k1 = *(const bf16x8*)&Ks[cb][32+l31][ch];
        s0 = __builtin_amdgcn_mfma_f32_32x32x16_bf16(k0, aq[kc], s0, 0,0,0);
        s1 = __builtin_amdgcn_mfma_f32_32x32x16_bf16(k1, aq[kc], s1, 0,0,0);
      }
      __builtin_amdgcn_s_setprio(0);
      // p = exp2(s) (Q pre-scaled); causal mask only on each wave's final tile
      if (j == jmax){
        const int qrel = ((wv&1)<<5) + l31;   // q - j*64, in-tile key limit
        #pragma unroll
        for (int r=0;r<16;r++){
          const int koff = (r&3) + 8*(r>>2) + 4*hi;
          s0[r] = (koff      <= qrel) ? exp2f(s0[r]) : 0.f;
          s1[r] = (32 + koff <= qrel) ? exp2f(s1[r]) : 0.f;
        }
      } else {
        #pragma unroll
        for (int r=0;r<16;r++){ s0[r] = exp2f(s0[r]); s1[r] = exp2f(s1[r]); }
      }
      #pragma unroll
      for (int r=0;r<16;r++) l_r += s0[r] + s1[r];
      // O^T += V^T P : P fragment built in-register (cvt_pk + permlane32_swap)
      __builtin_amdgcn_s_setprio(1);
      PV_CHUNK(s0, 0, 0); PV_CHUNK(s0, 0, 1);
      PV_CHUNK(s1, 1, 0); PV_CHUNK(s1, 1, 1);
      __builtin_amdgcn_s_setprio(0);
    }
  }
  // denominator: lane and lane^32 hold disjoint key sets for the same q
  float rs = l_r + __shfl_xor(l_r, 32);
  const float linv = 1.0f / rs;
  const int bb = bh>>4, hh = bh&15;
  const int q = q0 + l31;
  unsigned short* yrow = Yb + (size_t)(bb*T_ + q)*C_ + hh*64;
  #pragma unroll
  for (int g=0; g<4; g++){
    ushort4 y;
    y.x = f2bf(o0[4*g+0]*linv); y.y = f2bf(o0[4*g+1]*linv);
    y.z = f2bf(o0[4*g+2]*linv); y.w = f2bf(o0[4*g+3]*linv);
    *(ushort4*)&yrow[g*8 + hi*4] = y;
    ushort4 z;
    z.x = f2bf(o1[4*g+0]*linv); z.y = f2bf(o1[4*g+1]*linv);
    z.z = f2bf(o1[4*g+2]*linv); z.w = f2bf(o1[4*g+3]*linv);
    *(ushort4*)&yrow[32 + g*8 + hi*4] = z;
  }
}

// ---------------- proj GEMM (m97-style): Yb x Wpt^T -> fp32 out + bias ------
// T1 swizzle: flat grid 512 (512%8==0 -> bijective chunked swizzle).
__global__ __launch_bounds__(256) void proj_gemm(
    const unsigned short* __restrict__ Yb, const unsigned short* __restrict__ Wt,
    const float* __restrict__ bias, float* __restrict__ Out)
{
  __shared__ __align__(16) unsigned short As[128][32];
  __shared__ __align__(16) unsigned short Bs[128][32];
  const int tid = threadIdx.x;
  const int nbx = C_/128;                        // 8
  const int cpx = (nbx*(M_/128))/8;              // 64 tiles per XCD
  const int id0 = (int)blockIdx.x;
  const int swz = (id0 & 7)*cpx + (id0 >> 3);
  const int m0 = (swz / nbx)*128, n0 = (swz % nbx)*128;
  const int wv = tid>>6, lane = tid&63, lm = lane&15, lq = lane>>4;
  const int wr = wv>>1, wc = wv&1;
  f32x4 acc[4][4] = {};
  const int schunk = (lane&3) ^ ((lane>>3)&3);
  const unsigned short* gA = Yb + (size_t)(m0 + wv*32 + (lane>>2))*C_ + schunk*8;
  const unsigned short* gB = Wt + (size_t)(n0 + wv*32 + (lane>>2))*C_ + schunk*8;
  unsigned short* lA0 = &As[wv*32][0];
  unsigned short* lA1 = &As[wv*32+16][0];
  unsigned short* lB0 = &Bs[wv*32][0];
  unsigned short* lB1 = &Bs[wv*32+16][0];
  const int rkey = (lm>>1)&3;
  for (int k0=0;k0<C_;k0+=32){
    __syncthreads();
    gload_lds16(gA + k0,            lA0);
    gload_lds16(gA + 16*C_ + k0,    lA1);
    gload_lds16(gB + k0,            lB0);
    gload_lds16(gB + 16*C_ + k0,    lB1);
    __syncthreads();
    bf16x8 a[4], b[4];
    #pragma unroll
    for (int mt=0;mt<4;mt++) a[mt] = *(const bf16x8*)&As[wr*64+mt*16+lm][(lq^rkey)*8];
    #pragma unroll
    for (int nt=0;nt<4;nt++) b[nt] = *(const bf16x8*)&Bs[wc*64+nt*16+lm][(lq^rkey)*8];
    #pragma unroll
    for (int mt=0;mt<4;mt++)
      #pragma unroll
      for (int nt=0;nt<4;nt++)
        acc[mt][nt] = __builtin_amdgcn_mfma_f32_16x16x32_bf16(a[mt], b[nt], acc[mt][nt], 0,0,0);
  }
  #pragma unroll
  for (int mt=0;mt<4;mt++){
    const int grow = m0 + wr*64 + mt*16 + lq*4;
    #pragma unroll
    for (int nt=0;nt<4;nt++){
      const int gcol = n0 + wc*64 + nt*16 + lm;
      const float bv = bias[gcol];
      #pragma unroll
      for (int r=0;r<4;r++)
        Out[(size_t)(grow+r)*C_ + gcol] = acc[mt][nt][r] + bv;
    }
  }
}

extern "C" void kernel_launch(void* const* d_in, const int* in_sizes, int n_in,
                              void* d_out, int out_size, void* d_ws, size_t ws_size,
                              hipStream_t stream)
{
  const float* x      = (const float*)d_in[0];
  const float* W_attn = (const float*)d_in[1];
  const float* b_attn = (const float*)d_in[2];
  const float* W_proj = (const float*)d_in[3];
  const float* b_proj = (const float*)d_in[4];
  float* out = (float*)d_out;

  unsigned short* Wat = (unsigned short*)d_ws;            // [3072][1024] bf16
  unsigned short* Wpt = Wat + (size_t)N3_*C_;             // [1024][1024] bf16
  unsigned short* Xb  = Wpt + (size_t)C_*C_;              // [M,1024]  bf16
  unsigned short* Qb  = Xb  + (size_t)M_*C_;              // [B,H,T,D] bf16 (pre-scaled)
  unsigned short* Kb  = Qb  + (size_t)M_*C_;              // [B,H,T,D] bf16
  unsigned short* Vt  = Kb  + (size_t)M_*C_;              // [B,H,D,T] bf16
  unsigned short* Yb  = Vt  + (size_t)M_*C_;              // [M,1024]  bf16
  (void)ws_size; (void)in_sizes; (void)n_in; (void)out_size;

  x_cvt        <<<dim3(M_*C_/2048),        256, 0, stream>>>(x, Xb);
  transpose_cvt<<<dim3(N3_/32, C_/32),     256, 0, stream>>>(W_attn, Wat, C_, N3_);
  transpose_cvt<<<dim3(C_/32,  C_/32),     256, 0, stream>>>(W_proj, Wpt, C_, C_);
  qkv_gemm     <<<dim3((N3_/128)*(M_/128)), 256, 0, stream>>>(Xb, Wat, b_attn, Qb, Kb, Vt);
  flash_attn   <<<dim3(1024),              256, 0, stream>>>(Qb, Kb, Vt, Yb);
  proj_gemm    <<<dim3((C_/128)*(M_/128)),  256, 0, stream>>>(Yb, Wpt, b_proj, out);
}

// Round 10
// 240.950 us; speedup vs baseline: 1.0971x; 1.0426x over previous
//
#include <hip/hip_runtime.h>
#include <hip/hip_bf16.h>

#define B_ 4
#define T_ 2048
#define C_ 1024
#define H_ 16
#define D_ 64
#define N3_ 3072
#define M_ (B_*T_)

typedef __bf16 bf16x8 __attribute__((ext_vector_type(8)));
typedef float f32x4 __attribute__((ext_vector_type(4)));
typedef float f32x16 __attribute__((ext_vector_type(16)));

__device__ __forceinline__ unsigned short f2bf(float f){
  __bf16 h = (__bf16)f;              // RNE fptrunc -> v_cvt on gfx950
  return __builtin_bit_cast(unsigned short, h);
}
__device__ __forceinline__ unsigned int pk2(float a, float b){
  return (unsigned int)f2bf(a) | ((unsigned int)f2bf(b)<<16);
}
// async global->LDS, 16B per lane; LDS dest = base + lane*16 (wave-uniform base)
__device__ __forceinline__ void gload_lds16(const unsigned short* g, unsigned short* l){
  __builtin_amdgcn_global_load_lds(
      (const __attribute__((address_space(1))) void*)g,
      (__attribute__((address_space(3))) void*)l, 16, 0, 0);
}

// ---------------- fused prep: x cvt + both weight transposes ----------------
// 6 -> 4 dispatches: ~10us launch overhead per dispatch (rocprof.md) was ~60us
// of the 251us wall vs ~178us kernel-sum. Block-uniform branch on blockIdx.
__device__ __forceinline__ void tr_tile(
    const float* __restrict__ src, unsigned short* __restrict__ dst,
    int K, int N, int bx, int by, float tile[32][33])
{
  const int tx = threadIdx.x & 31, ty = threadIdx.x >> 5; // 32 x 8
  const int nt = bx * 32, kt = by * 32;
  #pragma unroll
  for (int i=0;i<32;i+=8) tile[ty+i][tx] = src[(size_t)(kt+ty+i)*N + nt+tx];
  __syncthreads();
  #pragma unroll
  for (int i=0;i<32;i+=8) dst[(size_t)(nt+ty+i)*K + kt+tx] = f2bf(tile[tx][ty+i]);
}

#define XCVT_BLKS (M_*C_/2048)          // 4096
#define TRA_BLKS  ((N3_/32)*(C_/32))    // 3072
#define TRP_BLKS  ((C_/32)*(C_/32))     // 1024

__global__ __launch_bounds__(256) void prep(
    const float* __restrict__ X,  unsigned short* __restrict__ Xb,
    const float* __restrict__ Wa, unsigned short* __restrict__ Wat,
    const float* __restrict__ Wp, unsigned short* __restrict__ Wpt)
{
  __shared__ float tile[32][33];
  const int bid = (int)blockIdx.x;
  if (bid < XCVT_BLKS){
    const size_t i = ((size_t)bid*256 + threadIdx.x)*8;
    float4 f0 = *(const float4*)(X+i);
    float4 f1 = *(const float4*)(X+i+4);
    uint4 w = make_uint4(pk2(f0.x,f0.y), pk2(f0.z,f0.w), pk2(f1.x,f1.y), pk2(f1.z,f1.w));
    *(uint4*)(Xb+i) = w;
  } else if (bid < XCVT_BLKS + TRA_BLKS){
    const int t = bid - XCVT_BLKS;
    tr_tile(Wa, Wat, C_, N3_, t % (N3_/32), t / (N3_/32), tile);
  } else {
    const int t = bid - (XCVT_BLKS + TRA_BLKS);
    tr_tile(Wp, Wpt, C_, C_, t % (C_/32), t / (C_/32), tile);
  }
}

// ---------------- QKV GEMM (m97-style global_load_lds staging) --------------
// T1 (m192): XCD-chunked swizzle on flat grid 1536 (1536%8==0 -> bijective).
__global__ __launch_bounds__(256) void qkv_gemm(
    const unsigned short* __restrict__ Xb, const unsigned short* __restrict__ Wt,
    const float* __restrict__ bias,
    unsigned short* __restrict__ Qb, unsigned short* __restrict__ Kb,
    unsigned short* __restrict__ Vt)
{
  __shared__ __align__(16) unsigned short As[128][32];
  __shared__ __align__(16) unsigned short Bs[128][32];
  const int tid = threadIdx.x;
  const int nbx = N3_/128;                       // 24
  const int cpx = (nbx*(M_/128))/8;              // 192 tiles per XCD
  const int id0 = (int)blockIdx.x;
  const int swz = (id0 & 7)*cpx + (id0 >> 3);
  const int m0 = (swz / nbx)*128, n0 = (swz % nbx)*128;
  const int wv = tid>>6, lane = tid&63, lm = lane&15, lq = lane>>4;
  const int wr = wv>>1, wc = wv&1;
  f32x4 acc[4][4] = {};
  const int schunk = (lane&3) ^ ((lane>>3)&3);
  const unsigned short* gA = Xb + (size_t)(m0 + wv*32 + (lane>>2))*C_ + schunk*8;
  const unsigned short* gB = Wt + (size_t)(n0 + wv*32 + (lane>>2))*C_ + schunk*8;
  unsigned short* lA0 = &As[wv*32][0];
  unsigned short* lA1 = &As[wv*32+16][0];
  unsigned short* lB0 = &Bs[wv*32][0];
  unsigned short* lB1 = &Bs[wv*32+16][0];
  const int rkey = (lm>>1)&3;
  for (int k0=0;k0<C_;k0+=32){
    __syncthreads();
    gload_lds16(gA + k0,            lA0);
    gload_lds16(gA + 16*C_ + k0,    lA1);
    gload_lds16(gB + k0,            lB0);
    gload_lds16(gB + 16*C_ + k0,    lB1);
    __syncthreads();
    bf16x8 a[4], b[4];
    #pragma unroll
    for (int mt=0;mt<4;mt++) a[mt] = *(const bf16x8*)&As[wr*64+mt*16+lm][(lq^rkey)*8];
    #pragma unroll
    for (int nt=0;nt<4;nt++) b[nt] = *(const bf16x8*)&Bs[wc*64+nt*16+lm][(lq^rkey)*8];
    #pragma unroll
    for (int mt=0;mt<4;mt++)
      #pragma unroll
      for (int nt=0;nt<4;nt++)
        acc[mt][nt] = __builtin_amdgcn_mfma_f32_16x16x32_bf16(a[mt], b[nt], acc[mt][nt], 0,0,0);
  }
  const int sel = n0>>10;  // block-uniform: 0=Q,1=K,2=V
  const float qsc = (sel==0) ? 0.18033688f : 1.0f;  // 0.125*log2(e) folded into Q
  #pragma unroll
  for (int mt=0;mt<4;mt++){
    const int grow = m0 + wr*64 + mt*16 + lq*4;
    const int bb = grow>>11, tt0 = grow&2047;
    #pragma unroll
    for (int nt=0;nt<4;nt++){
      const int gcol = n0 + wc*64 + nt*16 + lm;
      const int hh = (gcol>>6)&15, dd = gcol&63;
      const float bv = bias[gcol];
      if (sel==2){
        ushort4 pv;
        pv.x = f2bf(acc[mt][nt][0] + bv);
        pv.y = f2bf(acc[mt][nt][1] + bv);
        pv.z = f2bf(acc[mt][nt][2] + bv);
        pv.w = f2bf(acc[mt][nt][3] + bv);
        *(ushort4*)&Vt[ ((size_t)(bb*H_+hh)*D_ + dd)*T_ + tt0 ] = pv;
      } else {
        unsigned short* dst = (sel==0) ? Qb : Kb;
        #pragma unroll
        for (int r=0;r<4;r++)
          dst[ ((size_t)(bb*H_+hh)*T_ + tt0 + r)*D_ + dd ] = f2bf((acc[mt][nt][r] + bv)*qsc);
      }
    }
  }
}

// ---------------- flash attention (32x32 swapped-QK^T, in-register P) -------
// Per block: 128 q-rows, 4 waves x 32 q each. Swapped QK^T: s = mfma(K, Q)
// -> lane holds P[key][q=lane&31] (m74/m101 D-layout). P -> PV B-frag built
// in-register via v_cvt_pk_bf16_f32 + v_permlane32_swap_b32 (T12): swap
// exchanges key-halves between lane and lane^32 (same q). No Ps LDS buffer,
// no scalar cvt/ds_write chain, denominator = in-lane sum + 1 shfl_xor(32).
// VERIFIED r7: 82 -> ~69us vs 16x16 predecessor.
#define PV_CHUNK(SV, KG, C16) do{                                              \
  unsigned int X0_, X1_, Y0_, Y1_;                                             \
  asm("v_cvt_pk_bf16_f32 %0, %1, %2" : "=v"(X0_)                               \
      : "v"((float)(SV)[(C16)*8+0]), "v"((float)(SV)[(C16)*8+1]));             \
  asm("v_cvt_pk_bf16_f32 %0, %1, %2" : "=v"(X1_)                               \
      : "v"((float)(SV)[(C16)*8+2]), "v"((float)(SV)[(C16)*8+3]));             \
  asm("v_cvt_pk_bf16_f32 %0, %1, %2" : "=v"(Y0_)                               \
      : "v"((float)(SV)[(C16)*8+4]), "v"((float)(SV)[(C16)*8+5]));             \
  asm("v_cvt_pk_bf16_f32 %0, %1, %2" : "=v"(Y1_)                               \
      : "v"((float)(SV)[(C16)*8+6]), "v"((float)(SV)[(C16)*8+7]));             \
  asm volatile("v_permlane32_swap_b32 %0, %1" : "+v"(X0_), "+v"(Y0_));         \
  asm volatile("v_permlane32_swap_b32 %0, %1" : "+v"(X1_), "+v"(Y1_));         \
  uint4 pw_ = make_uint4(X0_, X1_, Y0_, Y1_);                                  \
  bf16x8 pf_ = __builtin_bit_cast(bf16x8, pw_);                                \
  const int ch_ = (((KG)*4 + (C16)*2 + hi) ^ l7)*8;                            \
  bf16x8 v0_ = *(const bf16x8*)&Vs[cb][l31][ch_];                              \
  bf16x8 v1_ = *(const bf16x8*)&Vs[cb][32+l31][ch_];                           \
  o0 = __builtin_amdgcn_mfma_f32_32x32x16_bf16(v0_, pf_, o0, 0,0,0);           \
  o1 = __builtin_amdgcn_mfma_f32_32x32x16_bf16(v1_, pf_, o1, 0,0,0);           \
}while(0)

__global__ __launch_bounds__(256, 3) void flash_attn(
    const unsigned short* __restrict__ Qb, const unsigned short* __restrict__ Kb,
    const unsigned short* __restrict__ Vt, unsigned short* __restrict__ Yb)
{
  __shared__ __align__(16) unsigned short Ks[2][64][64]; // swizzled chunks
  __shared__ __align__(16) unsigned short Vs[2][64][64]; // V^T, swizzled
  const int tid = threadIdx.x;
  const int wv = tid>>6, lane = tid&63;
  const int l31 = lane & 31, hi = lane >> 5, l7 = lane & 7;
  const int id = (int)blockIdx.x;
  const int bh = id & 63;                 // XCD L2 locality: same bh set per XCD
  const int qblk = 15 - (id >> 6);        // heavy q-blocks first
  const int qb = qblk*128;
  const int q0 = qb + wv*32;
  const unsigned short* Qh = Qb + (size_t)bh*T_*D_;
  const unsigned short* Kh = Kb + (size_t)bh*T_*D_;
  const unsigned short* Vh = Vt + (size_t)bh*D_*T_;
  // Q fragments (B-operand): lane holds Q[q0+l31][kc*16 + hi*8 + 0..7]
  bf16x8 aq[4];
  #pragma unroll
  for (int kc=0;kc<4;kc++)
    aq[kc] = *(const bf16x8*)&Qh[(size_t)(q0+l31)*D_ + kc*16 + hi*8];
  f32x16 o0 = {}, o1 = {};   // O^T: rows d (o0: 0-31, o1: 32-63), col q=l31
  float l_r = 0.f;
  // staging: wave wv covers rows [wv*16, wv*16+16)
  const int srl = lane>>3;
  const int sc  = (lane&7) ^ srl;
  const unsigned short* kg = Kh + (size_t)(wv*16 + srl)*D_ + sc*8;
  const unsigned short* vg = Vh + (size_t)(wv*16 + srl)*T_ + sc*8;
  {
    unsigned short* lk = &Ks[0][wv*16][0];
    unsigned short* lv = &Vs[0][wv*16][0];
    gload_lds16(kg,        lk);
    gload_lds16(kg + 8*D_, lk + 8*64);
    gload_lds16(vg,        lv);
    gload_lds16(vg + 8*T_, lv + 8*64);
  }
  const int JT = 2*qblk + 2;
  const int jmax = 2*qblk + (wv>>1);  // waves 0,1 finish one tile early
  for (int j=0;j<JT;j++){
    const int cb = j&1;
    __syncthreads();   // drains this wave's DMA (tile j) + prev-iter LDS reads
    if (j < JT-1){     // prefetch tile j+1 (hidden under compute)
      unsigned short* lk = &Ks[cb^1][wv*16][0];
      unsigned short* lv = &Vs[cb^1][wv*16][0];
      gload_lds16(kg + (size_t)((j+1)*64  )*D_, lk);
      gload_lds16(kg + (size_t)((j+1)*64+8)*D_, lk + 8*64);
      gload_lds16(vg + (j+1)*64,                lv);
      gload_lds16(vg + 8*T_ + (j+1)*64,         lv + 8*64);
    }
    if (j <= jmax){    // wave-uniform skip of fully-masked final tile
      // S^T = K Q^T : lane holds P[key = kg*32 + (r&3)+8*(r>>2)+4*hi][q = q0+l31]
      f32x16 s0 = {}, s1 = {};
      __builtin_amdgcn_s_setprio(1);
      #pragma unroll
      for (int kc=0;kc<4;kc++){
        const int ch = ((kc*2+hi) ^ l7)*8;
        bf16x8 k0 = *(const bf16x8*)&Ks[cb][l31][ch];
        bf16x8 k1 = *(const bf16x8*)&Ks[cb][32+l31][ch];
        s0 = __builtin_amdgcn_mfma_f32_32x32x16_bf16(k0, aq[kc], s0, 0,0,0);
        s1 = __builtin_amdgcn_mfma_f32_32x32x16_bf16(k1, aq[kc], s1, 0,0,0);
      }
      __builtin_amdgcn_s_setprio(0);
      // p = exp2(s) (Q pre-scaled); causal mask only on each wave's final tile
      if (j == jmax){
        const int qrel = ((wv&1)<<5) + l31;   // q - j*64, in-tile key limit
        #pragma unroll
        for (int r=0;r<16;r++){
          const int koff = (r&3) + 8*(r>>2) + 4*hi;
          s0[r] = (koff      <= qrel) ? exp2f(s0[r]) : 0.f;
          s1[r] = (32 + koff <= qrel) ? exp2f(s1[r]) : 0.f;
        }
      } else {
        #pragma unroll
        for (int r=0;r<16;r++){ s0[r] = exp2f(s0[r]); s1[r] = exp2f(s1[r]); }
      }
      #pragma unroll
      for (int r=0;r<16;r++) l_r += s0[r] + s1[r];
      // O^T += V^T P : P fragment built in-register (cvt_pk + permlane32_swap)
      __builtin_amdgcn_s_setprio(1);
      PV_CHUNK(s0, 0, 0); PV_CHUNK(s0, 0, 1);
      PV_CHUNK(s1, 1, 0); PV_CHUNK(s1, 1, 1);
      __builtin_amdgcn_s_setprio(0);
    }
  }
  // denominator: lane and lane^32 hold disjoint key sets for the same q
  float rs = l_r + __shfl_xor(l_r, 32);
  const float linv = 1.0f / rs;
  const int bb = bh>>4, hh = bh&15;
  const int q = q0 + l31;
  unsigned short* yrow = Yb + (size_t)(bb*T_ + q)*C_ + hh*64;
  #pragma unroll
  for (int g=0; g<4; g++){
    ushort4 y;
    y.x = f2bf(o0[4*g+0]*linv); y.y = f2bf(o0[4*g+1]*linv);
    y.z = f2bf(o0[4*g+2]*linv); y.w = f2bf(o0[4*g+3]*linv);
    *(ushort4*)&yrow[g*8 + hi*4] = y;
    ushort4 z;
    z.x = f2bf(o1[4*g+0]*linv); z.y = f2bf(o1[4*g+1]*linv);
    z.z = f2bf(o1[4*g+2]*linv); z.w = f2bf(o1[4*g+3]*linv);
    *(ushort4*)&yrow[32 + g*8 + hi*4] = z;
  }
}

// ---------------- proj GEMM (m97-style): Yb x Wpt^T -> fp32 out + bias ------
// T1 swizzle: flat grid 512 (512%8==0 -> bijective chunked swizzle).
__global__ __launch_bounds__(256) void proj_gemm(
    const unsigned short* __restrict__ Yb, const unsigned short* __restrict__ Wt,
    const float* __restrict__ bias, float* __restrict__ Out)
{
  __shared__ __align__(16) unsigned short As[128][32];
  __shared__ __align__(16) unsigned short Bs[128][32];
  const int tid = threadIdx.x;
  const int nbx = C_/128;                        // 8
  const int cpx = (nbx*(M_/128))/8;              // 64 tiles per XCD
  const int id0 = (int)blockIdx.x;
  const int swz = (id0 & 7)*cpx + (id0 >> 3);
  const int m0 = (swz / nbx)*128, n0 = (swz % nbx)*128;
  const int wv = tid>>6, lane = tid&63, lm = lane&15, lq = lane>>4;
  const int wr = wv>>1, wc = wv&1;
  f32x4 acc[4][4] = {};
  const int schunk = (lane&3) ^ ((lane>>3)&3);
  const unsigned short* gA = Yb + (size_t)(m0 + wv*32 + (lane>>2))*C_ + schunk*8;
  const unsigned short* gB = Wt + (size_t)(n0 + wv*32 + (lane>>2))*C_ + schunk*8;
  unsigned short* lA0 = &As[wv*32][0];
  unsigned short* lA1 = &As[wv*32+16][0];
  unsigned short* lB0 = &Bs[wv*32][0];
  unsigned short* lB1 = &Bs[wv*32+16][0];
  const int rkey = (lm>>1)&3;
  for (int k0=0;k0<C_;k0+=32){
    __syncthreads();
    gload_lds16(gA + k0,            lA0);
    gload_lds16(gA + 16*C_ + k0,    lA1);
    gload_lds16(gB + k0,            lB0);
    gload_lds16(gB + 16*C_ + k0,    lB1);
    __syncthreads();
    bf16x8 a[4], b[4];
    #pragma unroll
    for (int mt=0;mt<4;mt++) a[mt] = *(const bf16x8*)&As[wr*64+mt*16+lm][(lq^rkey)*8];
    #pragma unroll
    for (int nt=0;nt<4;nt++) b[nt] = *(const bf16x8*)&Bs[wc*64+nt*16+lm][(lq^rkey)*8];
    #pragma unroll
    for (int mt=0;mt<4;mt++)
      #pragma unroll
      for (int nt=0;nt<4;nt++)
        acc[mt][nt] = __builtin_amdgcn_mfma_f32_16x16x32_bf16(a[mt], b[nt], acc[mt][nt], 0,0,0);
  }
  #pragma unroll
  for (int mt=0;mt<4;mt++){
    const int grow = m0 + wr*64 + mt*16 + lq*4;
    #pragma unroll
    for (int nt=0;nt<4;nt++){
      const int gcol = n0 + wc*64 + nt*16 + lm;
      const float bv = bias[gcol];
      #pragma unroll
      for (int r=0;r<4;r++)
        Out[(size_t)(grow+r)*C_ + gcol] = acc[mt][nt][r] + bv;
    }
  }
}

extern "C" void kernel_launch(void* const* d_in, const int* in_sizes, int n_in,
                              void* d_out, int out_size, void* d_ws, size_t ws_size,
                              hipStream_t stream)
{
  const float* x      = (const float*)d_in[0];
  const float* W_attn = (const float*)d_in[1];
  const float* b_attn = (const float*)d_in[2];
  const float* W_proj = (const float*)d_in[3];
  const float* b_proj = (const float*)d_in[4];
  float* out = (float*)d_out;

  unsigned short* Wat = (unsigned short*)d_ws;            // [3072][1024] bf16
  unsigned short* Wpt = Wat + (size_t)N3_*C_;             // [1024][1024] bf16
  unsigned short* Xb  = Wpt + (size_t)C_*C_;              // [M,1024]  bf16
  unsigned short* Qb  = Xb  + (size_t)M_*C_;              // [B,H,T,D] bf16 (pre-scaled)
  unsigned short* Kb  = Qb  + (size_t)M_*C_;              // [B,H,T,D] bf16
  unsigned short* Vt  = Kb  + (size_t)M_*C_;              // [B,H,D,T] bf16
  unsigned short* Yb  = Vt  + (size_t)M_*C_;              // [M,1024]  bf16
  (void)ws_size; (void)in_sizes; (void)n_in; (void)out_size;

  prep      <<<dim3(XCVT_BLKS+TRA_BLKS+TRP_BLKS), 256, 0, stream>>>(
                x, Xb, W_attn, Wat, W_proj, Wpt);
  qkv_gemm  <<<dim3((N3_/128)*(M_/128)), 256, 0, stream>>>(Xb, Wat, b_attn, Qb, Kb, Vt);
  flash_attn<<<dim3(1024),               256, 0, stream>>>(Qb, Kb, Vt, Yb);
  proj_gemm <<<dim3((C_/128)*(M_/128)),  256, 0, stream>>>(Yb, Wpt, b_proj, out);
}

// Round 12
// 238.839 us; speedup vs baseline: 1.1068x; 1.0088x over previous
//
#include <hip/hip_runtime.h>
#include <hip/hip_bf16.h>

#define B_ 4
#define T_ 2048
#define C_ 1024
#define H_ 16
#define D_ 64
#define N3_ 3072
#define M_ (B_*T_)

typedef __bf16 bf16x8 __attribute__((ext_vector_type(8)));
typedef float f32x4 __attribute__((ext_vector_type(4)));
typedef float f32x16 __attribute__((ext_vector_type(16)));

__device__ __forceinline__ unsigned short f2bf(float f){
  __bf16 h = (__bf16)f;              // RNE fptrunc -> v_cvt on gfx950
  return __builtin_bit_cast(unsigned short, h);
}
__device__ __forceinline__ unsigned int pk2(float a, float b){
  return (unsigned int)f2bf(a) | ((unsigned int)f2bf(b)<<16);
}
// async global->LDS, 16B per lane; LDS dest = base + lane*16 (wave-uniform base)
__device__ __forceinline__ void gload_lds16(const unsigned short* g, unsigned short* l){
  __builtin_amdgcn_global_load_lds(
      (const __attribute__((address_space(1))) void*)g,
      (__attribute__((address_space(3))) void*)l, 16, 0, 0);
}

// ---------------- fused prep: x cvt + both weight transposes ----------------
// VERIFIED r10: 6 -> 4 dispatches = -10.3us (per-gap ~5us).
__device__ __forceinline__ void tr_tile(
    const float* __restrict__ src, unsigned short* __restrict__ dst,
    int K, int N, int bx, int by, float tile[32][33])
{
  const int tx = threadIdx.x & 31, ty = threadIdx.x >> 5; // 32 x 8
  const int nt = bx * 32, kt = by * 32;
  #pragma unroll
  for (int i=0;i<32;i+=8) tile[ty+i][tx] = src[(size_t)(kt+ty+i)*N + nt+tx];
  __syncthreads();
  #pragma unroll
  for (int i=0;i<32;i+=8) dst[(size_t)(nt+ty+i)*K + kt+tx] = f2bf(tile[tx][ty+i]);
}

#define XCVT_BLKS (M_*C_/2048)          // 4096
#define TRA_BLKS  ((N3_/32)*(C_/32))    // 3072
#define TRP_BLKS  ((C_/32)*(C_/32))     // 1024

__global__ __launch_bounds__(256) void prep(
    const float* __restrict__ X,  unsigned short* __restrict__ Xb,
    const float* __restrict__ Wa, unsigned short* __restrict__ Wat,
    const float* __restrict__ Wp, unsigned short* __restrict__ Wpt)
{
  __shared__ float tile[32][33];
  const int bid = (int)blockIdx.x;
  if (bid < XCVT_BLKS){
    const size_t i = ((size_t)bid*256 + threadIdx.x)*8;
    float4 f0 = *(const float4*)(X+i);
    float4 f1 = *(const float4*)(X+i+4);
    uint4 w = make_uint4(pk2(f0.x,f0.y), pk2(f0.z,f0.w), pk2(f1.x,f1.y), pk2(f1.z,f1.w));
    *(uint4*)(Xb+i) = w;
  } else if (bid < XCVT_BLKS + TRA_BLKS){
    const int t = bid - XCVT_BLKS;
    tr_tile(Wa, Wat, C_, N3_, t % (N3_/32), t / (N3_/32), tile);
  } else {
    const int t = bid - (XCVT_BLKS + TRA_BLKS);
    tr_tile(Wp, Wpt, C_, C_, t % (C_/32), t / (C_/32), tile);
  }
}

// ---------------- QKV GEMM: BK=64 re-tiling of the verified m97 structure ---
// r11: halve barrier-pair count (32->16), 32 MFMA per barrier window.
// LDS 32KB single-buffer. Swizzle for 64-col rows (stride=128B=bank period):
// store slot (lane&7) holds src chunk (lane&7)^(lane>>3) = slot^(row&7);
// read slot (kk*4+lq)^(lm&7) recovers chunk kk*4+lq; 8 lanes/4-bank group
// across all 32 banks = ds_read_b128 structural minimum (no excess conflict).
// T1 (m192): XCD-chunked swizzle on flat grid 1536 (1536%8==0 -> bijective).
__global__ __launch_bounds__(256) void qkv_gemm(
    const unsigned short* __restrict__ Xb, const unsigned short* __restrict__ Wt,
    const float* __restrict__ bias,
    unsigned short* __restrict__ Qb, unsigned short* __restrict__ Kb,
    unsigned short* __restrict__ Vt)
{
  __shared__ __align__(16) unsigned short As[128][64];
  __shared__ __align__(16) unsigned short Bs[128][64];
  const int tid = threadIdx.x;
  const int nbx = N3_/128;                       // 24
  const int cpx = (nbx*(M_/128))/8;              // 192 tiles per XCD
  const int id0 = (int)blockIdx.x;
  const int swz = (id0 & 7)*cpx + (id0 >> 3);
  const int m0 = (swz / nbx)*128, n0 = (swz % nbx)*128;
  const int wv = tid>>6, lane = tid&63, lm = lane&15, lq = lane>>4;
  const int wr = wv>>1, wc = wv&1;
  f32x4 acc[4][4] = {};
  const int srow = lane>>3;                      // 0..7
  const int sc   = (lane&7) ^ srow;              // source chunk = slot^(row&7)
  const unsigned short* gA = Xb + (size_t)(m0 + wv*32 + srow)*C_ + sc*8;
  const unsigned short* gB = Wt + (size_t)(n0 + wv*32 + srow)*C_ + sc*8;
  unsigned short* lA = &As[wv*32][0];
  unsigned short* lB = &Bs[wv*32][0];
  const int key = lm&7;
  for (int k0=0;k0<C_;k0+=64){
    __syncthreads();
    #pragma unroll
    for (int i=0;i<4;i++){
      gload_lds16(gA + (size_t)i*8*C_ + k0, lA + i*8*64);
      gload_lds16(gB + (size_t)i*8*C_ + k0, lB + i*8*64);
    }
    __syncthreads();
    #pragma unroll
    for (int kk=0;kk<2;kk++){
      bf16x8 a[4], b[4];
      #pragma unroll
      for (int mt=0;mt<4;mt++) a[mt] = *(const bf16x8*)&As[wr*64+mt*16+lm][((kk*4+lq)^key)*8];
      #pragma unroll
      for (int nt=0;nt<4;nt++) b[nt] = *(const bf16x8*)&Bs[wc*64+nt*16+lm][((kk*4+lq)^key)*8];
      #pragma unroll
      for (int mt=0;mt<4;mt++)
        #pragma unroll
        for (int nt=0;nt<4;nt++)
          acc[mt][nt] = __builtin_amdgcn_mfma_f32_16x16x32_bf16(a[mt], b[nt], acc[mt][nt], 0,0,0);
    }
  }
  const int sel = n0>>10;  // block-uniform: 0=Q,1=K,2=V
  const float qsc = (sel==0) ? 0.18033688f : 1.0f;  // 0.125*log2(e) folded into Q
  #pragma unroll
  for (int mt=0;mt<4;mt++){
    const int grow = m0 + wr*64 + mt*16 + lq*4;
    const int bb = grow>>11, tt0 = grow&2047;
    #pragma unroll
    for (int nt=0;nt<4;nt++){
      const int gcol = n0 + wc*64 + nt*16 + lm;
      const int hh = (gcol>>6)&15, dd = gcol&63;
      const float bv = bias[gcol];
      if (sel==2){
        ushort4 pv;
        pv.x = f2bf(acc[mt][nt][0] + bv);
        pv.y = f2bf(acc[mt][nt][1] + bv);
        pv.z = f2bf(acc[mt][nt][2] + bv);
        pv.w = f2bf(acc[mt][nt][3] + bv);
        *(ushort4*)&Vt[ ((size_t)(bb*H_+hh)*D_ + dd)*T_ + tt0 ] = pv;
      } else {
        unsigned short* dst = (sel==0) ? Qb : Kb;
        #pragma unroll
        for (int r=0;r<4;r++)
          dst[ ((size_t)(bb*H_+hh)*T_ + tt0 + r)*D_ + dd ] = f2bf((acc[mt][nt][r] + bv)*qsc);
      }
    }
  }
}

// ---------------- flash attention (32x32 swapped-QK^T, in-register P) -------
// VERIFIED r7: 82 -> ~69us vs 16x16 predecessor.
#define PV_CHUNK(SV, KG, C16) do{                                              \
  unsigned int X0_, X1_, Y0_, Y1_;                                             \
  asm("v_cvt_pk_bf16_f32 %0, %1, %2" : "=v"(X0_)                               \
      : "v"((float)(SV)[(C16)*8+0]), "v"((float)(SV)[(C16)*8+1]));             \
  asm("v_cvt_pk_bf16_f32 %0, %1, %2" : "=v"(X1_)                               \
      : "v"((float)(SV)[(C16)*8+2]), "v"((float)(SV)[(C16)*8+3]));             \
  asm("v_cvt_pk_bf16_f32 %0, %1, %2" : "=v"(Y0_)                               \
      : "v"((float)(SV)[(C16)*8+4]), "v"((float)(SV)[(C16)*8+5]));             \
  asm("v_cvt_pk_bf16_f32 %0, %1, %2" : "=v"(Y1_)                               \
      : "v"((float)(SV)[(C16)*8+6]), "v"((float)(SV)[(C16)*8+7]));             \
  asm volatile("v_permlane32_swap_b32 %0, %1" : "+v"(X0_), "+v"(Y0_));         \
  asm volatile("v_permlane32_swap_b32 %0, %1" : "+v"(X1_), "+v"(Y1_));         \
  uint4 pw_ = make_uint4(X0_, X1_, Y0_, Y1_);                                  \
  bf16x8 pf_ = __builtin_bit_cast(bf16x8, pw_);                                \
  const int ch_ = (((KG)*4 + (C16)*2 + hi) ^ l7)*8;                            \
  bf16x8 v0_ = *(const bf16x8*)&Vs[cb][l31][ch_];                              \
  bf16x8 v1_ = *(const bf16x8*)&Vs[cb][32+l31][ch_];                           \
  o0 = __builtin_amdgcn_mfma_f32_32x32x16_bf16(v0_, pf_, o0, 0,0,0);           \
  o1 = __builtin_amdgcn_mfma_f32_32x32x16_bf16(v1_, pf_, o1, 0,0,0);           \
}while(0)

__global__ __launch_bounds__(256, 3) void flash_attn(
    const unsigned short* __restrict__ Qb, const unsigned short* __restrict__ Kb,
    const unsigned short* __restrict__ Vt, unsigned short* __restrict__ Yb)
{
  __shared__ __align__(16) unsigned short Ks[2][64][64]; // swizzled chunks
  __shared__ __align__(16) unsigned short Vs[2][64][64]; // V^T, swizzled
  const int tid = threadIdx.x;
  const int wv = tid>>6, lane = tid&63;
  const int l31 = lane & 31, hi = lane >> 5, l7 = lane & 7;
  const int id = (int)blockIdx.x;
  const int bh = id & 63;                 // XCD L2 locality: same bh set per XCD
  const int qblk = 15 - (id >> 6);        // heavy q-blocks first
  const int qb = qblk*128;
  const int q0 = qb + wv*32;
  const unsigned short* Qh = Qb + (size_t)bh*T_*D_;
  const unsigned short* Kh = Kb + (size_t)bh*T_*D_;
  const unsigned short* Vh = Vt + (size_t)bh*D_*T_;
  // Q fragments (B-operand): lane holds Q[q0+l31][kc*16 + hi*8 + 0..7]
  bf16x8 aq[4];
  #pragma unroll
  for (int kc=0;kc<4;kc++)
    aq[kc] = *(const bf16x8*)&Qh[(size_t)(q0+l31)*D_ + kc*16 + hi*8];
  f32x16 o0 = {}, o1 = {};   // O^T: rows d (o0: 0-31, o1: 32-63), col q=l31
  float l_r = 0.f;
  // staging: wave wv covers rows [wv*16, wv*16+16)
  const int srl = lane>>3;
  const int sc  = (lane&7) ^ srl;
  const unsigned short* kg = Kh + (size_t)(wv*16 + srl)*D_ + sc*8;
  const unsigned short* vg = Vh + (size_t)(wv*16 + srl)*T_ + sc*8;
  {
    unsigned short* lk = &Ks[0][wv*16][0];
    unsigned short* lv = &Vs[0][wv*16][0];
    gload_lds16(kg,        lk);
    gload_lds16(kg + 8*D_, lk + 8*64);
    gload_lds16(vg,        lv);
    gload_lds16(vg + 8*T_, lv + 8*64);
  }
  const int JT = 2*qblk + 2;
  const int jmax = 2*qblk + (wv>>1);  // waves 0,1 finish one tile early
  for (int j=0;j<JT;j++){
    const int cb = j&1;
    __syncthreads();   // drains this wave's DMA (tile j) + prev-iter LDS reads
    if (j < JT-1){     // prefetch tile j+1 (hidden under compute)
      unsigned short* lk = &Ks[cb^1][wv*16][0];
      unsigned short* lv = &Vs[cb^1][wv*16][0];
      gload_lds16(kg + (size_t)((j+1)*64  )*D_, lk);
      gload_lds16(kg + (size_t)((j+1)*64+8)*D_, lk + 8*64);
      gload_lds16(vg + (j+1)*64,                lv);
      gload_lds16(vg + 8*T_ + (j+1)*64,         lv + 8*64);
    }
    if (j <= jmax){    // wave-uniform skip of fully-masked final tile
      // S^T = K Q^T : lane holds P[key = kg*32 + (r&3)+8*(r>>2)+4*hi][q = q0+l31]
      f32x16 s0 = {}, s1 = {};
      __builtin_amdgcn_s_setprio(1);
      #pragma unroll
      for (int kc=0;kc<4;kc++){
        const int ch = ((kc*2+hi) ^ l7)*8;
        bf16x8 k0 = *(const bf16x8*)&Ks[cb][l31][ch];
        bf16x8 k1 = *(const bf16x8*)&Ks[cb][32+l31][ch];
        s0 = __builtin_amdgcn_mfma_f32_32x32x16_bf16(k0, aq[kc], s0, 0,0,0);
        s1 = __builtin_amdgcn_mfma_f32_32x32x16_bf16(k1, aq[kc], s1, 0,0,0);
      }
      __builtin_amdgcn_s_setprio(0);
      // p = exp2(s) (Q pre-scaled); causal mask only on each wave's final tile
      if (j == jmax){
        const int qrel = ((wv&1)<<5) + l31;   // q - j*64, in-tile key limit
        #pragma unroll
        for (int r=0;r<16;r++){
          const int koff = (r&3) + 8*(r>>2) + 4*hi;
          s0[r] = (koff      <= qrel) ? exp2f(s0[r]) : 0.f;
          s1[r] = (32 + koff <= qrel) ? exp2f(s1[r]) : 0.f;
        }
      } else {
        #pragma unroll
        for (int r=0;r<16;r++){ s0[r] = exp2f(s0[r]); s1[r] = exp2f(s1[r]); }
      }
      #pragma unroll
      for (int r=0;r<16;r++) l_r += s0[r] + s1[r];
      // O^T += V^T P : P fragment built in-register (cvt_pk + permlane32_swap)
      __builtin_amdgcn_s_setprio(1);
      PV_CHUNK(s0, 0, 0); PV_CHUNK(s0, 0, 1);
      PV_CHUNK(s1, 1, 0); PV_CHUNK(s1, 1, 1);
      __builtin_amdgcn_s_setprio(0);
    }
  }
  // denominator: lane and lane^32 hold disjoint key sets for the same q
  float rs = l_r + __shfl_xor(l_r, 32);
  const float linv = 1.0f / rs;
  const int bb = bh>>4, hh = bh&15;
  const int q = q0 + l31;
  unsigned short* yrow = Yb + (size_t)(bb*T_ + q)*C_ + hh*64;
  #pragma unroll
  for (int g=0; g<4; g++){
    ushort4 y;
    y.x = f2bf(o0[4*g+0]*linv); y.y = f2bf(o0[4*g+1]*linv);
    y.z = f2bf(o0[4*g+2]*linv); y.w = f2bf(o0[4*g+3]*linv);
    *(ushort4*)&yrow[g*8 + hi*4] = y;
    ushort4 z;
    z.x = f2bf(o1[4*g+0]*linv); z.y = f2bf(o1[4*g+1]*linv);
    z.z = f2bf(o1[4*g+2]*linv); z.w = f2bf(o1[4*g+3]*linv);
    *(ushort4*)&yrow[32 + g*8 + hi*4] = z;
  }
}

// ---------------- proj GEMM: BK=64 re-tiling (same as qkv) ------------------
// T1 swizzle: flat grid 512 (512%8==0 -> bijective chunked swizzle).
__global__ __launch_bounds__(256) void proj_gemm(
    const unsigned short* __restrict__ Yb, const unsigned short* __restrict__ Wt,
    const float* __restrict__ bias, float* __restrict__ Out)
{
  __shared__ __align__(16) unsigned short As[128][64];
  __shared__ __align__(16) unsigned short Bs[128][64];
  const int tid = threadIdx.x;
  const int nbx = C_/128;                        // 8
  const int cpx = (nbx*(M_/128))/8;              // 64 tiles per XCD
  const int id0 = (int)blockIdx.x;
  const int swz = (id0 & 7)*cpx + (id0 >> 3);
  const int m0 = (swz / nbx)*128, n0 = (swz % nbx)*128;
  const int wv = tid>>6, lane = tid&63, lm = lane&15, lq = lane>>4;
  const int wr = wv>>1, wc = wv&1;
  f32x4 acc[4][4] = {};
  const int srow = lane>>3;
  const int sc   = (lane&7) ^ srow;
  const unsigned short* gA = Yb + (size_t)(m0 + wv*32 + srow)*C_ + sc*8;
  const unsigned short* gB = Wt + (size_t)(n0 + wv*32 + srow)*C_ + sc*8;
  unsigned short* lA = &As[wv*32][0];
  unsigned short* lB = &Bs[wv*32][0];
  const int key = lm&7;
  for (int k0=0;k0<C_;k0+=64){
    __syncthreads();
    #pragma unroll
    for (int i=0;i<4;i++){
      gload_lds16(gA + (size_t)i*8*C_ + k0, lA + i*8*64);
      gload_lds16(gB + (size_t)i*8*C_ + k0, lB + i*8*64);
    }
    __syncthreads();
    #pragma unroll
    for (int kk=0;kk<2;kk++){
      bf16x8 a[4], b[4];
      #pragma unroll
      for (int mt=0;mt<4;mt++) a[mt] = *(const bf16x8*)&As[wr*64+mt*16+lm][((kk*4+lq)^key)*8];
      #pragma unroll
      for (int nt=0;nt<4;nt++) b[nt] = *(const bf16x8*)&Bs[wc*64+nt*16+lm][((kk*4+lq)^key)*8];
      #pragma unroll
      for (int mt=0;mt<4;mt++)
        #pragma unroll
        for (int nt=0;nt<4;nt++)
          acc[mt][nt] = __builtin_amdgcn_mfma_f32_16x16x32_bf16(a[mt], b[nt], acc[mt][nt], 0,0,0);
    }
  }
  #pragma unroll
  for (int mt=0;mt<4;mt++){
    const int grow = m0 + wr*64 + mt*16 + lq*4;
    #pragma unroll
    for (int nt=0;nt<4;nt++){
      const int gcol = n0 + wc*64 + nt*16 + lm;
      const float bv = bias[gcol];
      #pragma unroll
      for (int r=0;r<4;r++)
        Out[(size_t)(grow+r)*C_ + gcol] = acc[mt][nt][r] + bv;
    }
  }
}

extern "C" void kernel_launch(void* const* d_in, const int* in_sizes, int n_in,
                              void* d_out, int out_size, void* d_ws, size_t ws_size,
                              hipStream_t stream)
{
  const float* x      = (const float*)d_in[0];
  const float* W_attn = (const float*)d_in[1];
  const float* b_attn = (const float*)d_in[2];
  const float* W_proj = (const float*)d_in[3];
  const float* b_proj = (const float*)d_in[4];
  float* out = (float*)d_out;

  unsigned short* Wat = (unsigned short*)d_ws;            // [3072][1024] bf16
  unsigned short* Wpt = Wat + (size_t)N3_*C_;             // [1024][1024] bf16
  unsigned short* Xb  = Wpt + (size_t)C_*C_;              // [M,1024]  bf16
  unsigned short* Qb  = Xb  + (size_t)M_*C_;              // [B,H,T,D] bf16 (pre-scaled)
  unsigned short* Kb  = Qb  + (size_t)M_*C_;              // [B,H,T,D] bf16
  unsigned short* Vt  = Kb  + (size_t)M_*C_;              // [B,H,D,T] bf16
  unsigned short* Yb  = Vt  + (size_t)M_*C_;              // [M,1024]  bf16
  (void)ws_size; (void)in_sizes; (void)n_in; (void)out_size;

  prep      <<<dim3(XCVT_BLKS+TRA_BLKS+TRP_BLKS), 256, 0, stream>>>(
                x, Xb, W_attn, Wat, W_proj, Wpt);
  qkv_gemm  <<<dim3((N3_/128)*(M_/128)), 256, 0, stream>>>(Xb, Wat, b_attn, Qb, Kb, Vt);
  flash_attn<<<dim3(1024),               256, 0, stream>>>(Qb, Kb, Vt, Yb);
  proj_gemm <<<dim3((C_/128)*(M_/128)),  256, 0, stream>>>(Yb, Wpt, b_proj, out);
}